// Round 12
// baseline (736.161 us; speedup 1.0000x reference)
//
#include <hip/hip_runtime.h>
#include <hip/hip_bf16.h>
#include <hip/hip_cooperative_groups.h>
#include <math.h>

namespace cg = cooperative_groups;

#define DIM 128
#define DFF 512
#define TTW 64
#define NPI 8
#define NTOK 9
#define TILE_H 32

typedef __attribute__((ext_vector_type(8))) short short8;
typedef __attribute__((ext_vector_type(4))) float float4v;

__device__ __forceinline__ float bf16lo_f32(unsigned u) {
    union { unsigned u; float f; } v; v.u = u << 16;
    return v.f;
}
__device__ __forceinline__ float bf16hi_f32(unsigned u) {
    union { unsigned u; float f; } v; v.u = u & 0xffff0000u;
    return v.f;
}
__device__ __forceinline__ unsigned pk_bf16(float a, float b) {  // -> a | b<<16
    __hip_bfloat162 h = __float22bfloat162_rn(float2{a, b});
    union { __hip_bfloat162 h; unsigned u; } cv; cv.h = h;
    return cv.u;
}

// ============ prep (fallback path): hf->bf16 + W1/W2 transposes ============
__global__ __launch_bounds__(256)
void prep_k(const float* __restrict__ hf, const float* __restrict__ W1,
            const float* __restrict__ W2,
            unsigned short* __restrict__ hf2, unsigned short* __restrict__ w1t,
            unsigned short* __restrict__ w2t,
            int n_hf, int B_HF)
{
    __shared__ float tile[32][33];
    const int b = blockIdx.x, t = threadIdx.x;
    if (b < B_HF) {
        int i = (b * 256 + t) * 8;
        if (i < n_hf) {
            float4v v0 = *(const float4v*)(hf + i);
            float4v v1 = *(const float4v*)(hf + i + 4);
            uint4 o;
            o.x = pk_bf16(v0[0], v0[1]);
            o.y = pk_bf16(v0[2], v0[3]);
            o.z = pk_bf16(v1[0], v1[1]);
            o.w = pk_bf16(v1[2], v1[3]);
            *(uint4*)(hf2 + i) = o;
        }
    } else if (b < B_HF + 64) {
        const int tb = b - B_HF;            // W1 [128][512] -> w1t bf16 [512][128]
        const int r0 = (tb & 3) * 32, c0 = (tb >> 2) * 32;
        const int ty = t >> 3, tx = t & 7;
        *(float4v*)&tile[ty][tx * 4] = *(const float4v*)(W1 + (r0 + ty) * DFF + c0 + tx * 4);
        __syncthreads();
        uint2 o;
        o.x = pk_bf16(tile[tx * 4 + 0][ty], tile[tx * 4 + 1][ty]);
        o.y = pk_bf16(tile[tx * 4 + 2][ty], tile[tx * 4 + 3][ty]);
        *(uint2*)(w1t + (c0 + ty) * DIM + r0 + tx * 4) = o;
    } else {
        const int tb = b - B_HF - 64;       // W2 [512][64] -> w2t bf16 [64][512]
        const int r0 = (tb & 15) * 32, c0 = (tb >> 4) * 32;
        const int ty = t >> 3, tx = t & 7;
        *(float4v*)&tile[ty][tx * 4] = *(const float4v*)(W2 + (r0 + ty) * TTW + c0 + tx * 4);
        __syncthreads();
        uint2 o;
        o.x = pk_bf16(tile[tx * 4 + 0][ty], tile[tx * 4 + 1][ty]);
        o.y = pk_bf16(tile[tx * 4 + 2][ty], tile[tx * 4 + 3][ty]);
        *(uint2*)(w2t + (c0 + ty) * DFF + r0 + tx * 4) = o;
    }
}

// ===== fused body (R11-proven, TILE_H=32): [COOP: phase0 + grid.sync] + tile loop =====
// __launch_bounds__(256,3): tighter bounds spill the fp32 accumulators
// (R7: WRITE_SIZE 37->214 MB = scratch). Separate Apool/Hsm (fastest measured).
template<bool COOP>
__global__ __launch_bounds__(256, 3)
void fused_t(const float* __restrict__ hf,
             const float* __restrict__ w_q,
             const int* __restrict__ pi,
             const int* __restrict__ stats,
             const int* __restrict__ po,
             const float* __restrict__ W1,
             const float* __restrict__ W2,
             const float* __restrict__ b1,
             const float* __restrict__ gamma,
             const float* __restrict__ beta,
             const float* __restrict__ b2,
             unsigned short* __restrict__ hf2,     // ws: bf16 node features
             unsigned short* __restrict__ w1t,     // ws: bf16 [512][128]
             unsigned short* __restrict__ w2t,     // ws: bf16 [64][512]
             float* __restrict__ out,
             int H, int ntiles, int n_hf)
{
    __shared__ __align__(16) unsigned short Apool[TILE_H][DIM + 8];   // 8704 B
    __shared__ __align__(16) unsigned short Hsm[TILE_H][DFF + 8];     // 33280 B
    __shared__ float part[2][16][4][2];                 // [ht][row][wave][sum,ssq]
    float (*tile)[33] = (float (*)[33])&Apool[0][0];    // phase-0 alias (4224 B)

    const int t    = threadIdx.x;
    const int lane = t & 63;
    const int w    = t >> 6;
    const int row  = lane & 15;
    const int quad = lane >> 4;

    if constexpr (COOP) {
        // ---- Phase 0: weight/feature conversion, then grid-wide sync ----
        const int stride = gridDim.x * 256 * 8;
        for (int i = (blockIdx.x * 256 + t) * 8; i < n_hf; i += stride) {
            float4v v0 = *(const float4v*)(hf + i);
            float4v v1 = *(const float4v*)(hf + i + 4);
            uint4 o;
            o.x = pk_bf16(v0[0], v0[1]);
            o.y = pk_bf16(v0[2], v0[3]);
            o.z = pk_bf16(v1[0], v1[1]);
            o.w = pk_bf16(v1[2], v1[3]);
            *(uint4*)(hf2 + i) = o;
        }
        if (blockIdx.x < 64) {
            const int tb = blockIdx.x;          // W1 [128][512] -> w1t bf16 [512][128]
            const int r0 = (tb & 3) * 32, c0 = (tb >> 2) * 32;
            const int ty = t >> 3, tx = t & 7;
            *(float4v*)&tile[ty][tx * 4] = *(const float4v*)(W1 + (r0 + ty) * DFF + c0 + tx * 4);
            __syncthreads();
            uint2 o;
            o.x = pk_bf16(tile[tx * 4 + 0][ty], tile[tx * 4 + 1][ty]);
            o.y = pk_bf16(tile[tx * 4 + 2][ty], tile[tx * 4 + 3][ty]);
            *(uint2*)(w1t + (c0 + ty) * DIM + r0 + tx * 4) = o;
        } else if (blockIdx.x < 96) {
            const int tb = blockIdx.x - 64;     // W2 [512][64] -> w2t bf16 [64][512]
            const int r0 = (tb & 15) * 32, c0 = (tb >> 4) * 32;
            const int ty = t >> 3, tx = t & 7;
            *(float4v*)&tile[ty][tx * 4] = *(const float4v*)(W2 + (r0 + ty) * TTW + c0 + tx * 4);
            __syncthreads();
            uint2 o;
            o.x = pk_bf16(tile[tx * 4 + 0][ty], tile[tx * 4 + 1][ty]);
            o.y = pk_bf16(tile[tx * 4 + 2][ty], tile[tx * 4 + 3][ty]);
            *(uint2*)(w2t + (c0 + ty) * DFF + r0 + tx * 4) = o;
        }
        __threadfence();             // device-scope release: publish ws across XCDs
        cg::this_grid().sync();
        __syncthreads();             // re-converge before Apool reuse (tile alias)
    }

    // ================= Tile loop (grid-strided; 1 iter in fallback) =================
    for (int tilei = blockIdx.x; tilei < ntiles; tilei += (COOP ? gridDim.x : ntiles + 1)) {
        const int hop0 = tilei * TILE_H;

        // -------- Phase 1: gather + masked attention pooling (32 lanes/hop) --------
        {
            const int g = t >> 5, l = t & 31;       // lane l owns dims 4l..4l+3
            const float4v wq4 = *(const float4v*)(w_q + l * 4);

            int idxs[4][NTOK];
            unsigned vm[4];
            #pragma unroll
            for (int it = 0; it < 4; ++it) {
                int hop = hop0 + g + it * 8;
                if (hop >= H) hop = H - 1;          // clamp; out stores are guarded
                int4 p0 = *(const int4*)(pi + hop * NPI);
                int4 p1 = *(const int4*)(pi + hop * NPI + 4);
                int4 s0 = *(const int4*)(stats + hop * NPI);
                int4 s1 = *(const int4*)(stats + hop * NPI + 4);
                idxs[it][0] = p0.x; idxs[it][1] = p0.y;
                idxs[it][2] = p0.z; idxs[it][3] = p0.w;
                idxs[it][4] = p1.x; idxs[it][5] = p1.y;
                idxs[it][6] = p1.z; idxs[it][7] = p1.w;
                idxs[it][8] = po[hop];
                vm[it] = (s0.x != -1 ? 1u   : 0u) | (s0.y != -1 ? 2u   : 0u)
                       | (s0.z != -1 ? 4u   : 0u) | (s0.w != -1 ? 8u   : 0u)
                       | (s1.x != -1 ? 16u  : 0u) | (s1.y != -1 ? 32u  : 0u)
                       | (s1.z != -1 ? 64u  : 0u) | (s1.w != -1 ? 128u : 0u)
                       | 256u;                      // PO always valid
            }
            uint2 tu[4][NTOK];
            #pragma unroll
            for (int it = 0; it < 4; ++it)
                #pragma unroll
                for (int p = 0; p < NTOK; ++p)
                    tu[it][p] = *(const uint2*)(hf2 + (size_t)idxs[it][p] * DIM + l * 4);

            #pragma unroll
            for (int it = 0; it < 4; ++it) {
                const int hl = g + it * 8;
                float tok[NTOK][4];
                #pragma unroll
                for (int p = 0; p < NTOK; ++p) {
                    tok[p][0] = bf16lo_f32(tu[it][p].x);
                    tok[p][1] = bf16hi_f32(tu[it][p].x);
                    tok[p][2] = bf16lo_f32(tu[it][p].y);
                    tok[p][3] = bf16hi_f32(tu[it][p].y);
                }
                float sc[NTOK];
                #pragma unroll
                for (int p = 0; p < NTOK; ++p)
                    sc[p] = tok[p][0]*wq4[0] + tok[p][1]*wq4[1]
                          + tok[p][2]*wq4[2] + tok[p][3]*wq4[3];
                #pragma unroll
                for (int m = 1; m < 32; m <<= 1) {
                    #pragma unroll
                    for (int p = 0; p < NTOK; ++p) sc[p] += __shfl_xor(sc[p], m);
                }
                const float isd = 0.08838834764831845f;   // 1/sqrt(128)
                float mx = -1e30f;
                #pragma unroll
                for (int p = 0; p < NTOK; ++p) {
                    sc[p] = ((vm[it] >> p) & 1u) ? sc[p] * isd : -1e30f;
                    mx = fmaxf(mx, sc[p]);
                }
                float se = 0.f;
                #pragma unroll
                for (int p = 0; p < NTOK; ++p) { sc[p] = __expf(sc[p] - mx); se += sc[p]; }
                const float inv = 1.f / se;
                float a0=0.f, a1=0.f, a2=0.f, a3=0.f;
                #pragma unroll
                for (int p = 0; p < NTOK; ++p) {
                    float a = sc[p] * inv;
                    a0 += a * tok[p][0]; a1 += a * tok[p][1];
                    a2 += a * tok[p][2]; a3 += a * tok[p][3];
                }
                uint2 o;
                o.x = pk_bf16(a0, a1);
                o.y = pk_bf16(a2, a3);
                *(uint2*)&Apool[hl][l * 4] = o;
            }
        }
        __syncthreads();

        // -------- GEMM1: A=W1T rows (out-dims), B=Apool^T (hops); all acc live --------
        float4v acc[8][2];
        #pragma unroll
        for (int mt = 0; mt < 8; ++mt) {
            acc[mt][0] = (float4v){0.f, 0.f, 0.f, 0.f};
            acc[mt][1] = (float4v){0.f, 0.f, 0.f, 0.f};
        }
        {
            short8 bfr[2][4];
            #pragma unroll
            for (int ks = 0; ks < 4; ++ks) {
                const int k0 = ks * 32 + quad * 8;
                #pragma unroll
                for (int ht = 0; ht < 2; ++ht)
                    bfr[ht][ks] = *(const short8*)&Apool[ht * 16 + row][k0];
            }
            #pragma unroll
            for (int mt = 0; mt < 8; ++mt) {
                const unsigned short* wrow = w1t + (size_t)(w * 128 + mt * 16 + row) * DIM;
                #pragma unroll
                for (int ks = 0; ks < 4; ++ks) {
                    short8 afr = *(const short8*)(wrow + ks * 32 + quad * 8);
                    acc[mt][0] = __builtin_amdgcn_mfma_f32_16x16x32_bf16(afr, bfr[0][ks], acc[mt][0], 0, 0, 0);
                    acc[mt][1] = __builtin_amdgcn_mfma_f32_16x16x32_bf16(afr, bfr[1][ks], acc[mt][1], 0, 0, 0);
                }
            }
        }
        // -------- pass 1: bias + ReLU in registers, LN stats --------
        float sum0 = 0.f, ssq0 = 0.f, sum1 = 0.f, ssq1 = 0.f;
        #pragma unroll
        for (int mt = 0; mt < 8; ++mt) {
            const int nb = w * 128 + mt * 16 + quad * 4;
            const float4v bias = *(const float4v*)(b1 + nb);
            #pragma unroll
            for (int r = 0; r < 4; ++r) {
                float v0 = fmaxf(acc[mt][0][r] + bias[r], 0.f);
                float v1 = fmaxf(acc[mt][1][r] + bias[r], 0.f);
                acc[mt][0][r] = v0;  sum0 += v0;  ssq0 += v0 * v0;
                acc[mt][1][r] = v1;  sum1 += v1;  ssq1 += v1 * v1;
            }
        }
        #pragma unroll
        for (int m = 16; m <= 32; m <<= 1) {       // reduce across the 4 quads
            sum0 += __shfl_xor(sum0, m);  ssq0 += __shfl_xor(ssq0, m);
            sum1 += __shfl_xor(sum1, m);  ssq1 += __shfl_xor(ssq1, m);
        }
        if (lane < 16) {
            part[0][row][w][0] = sum0;  part[0][row][w][1] = ssq0;
            part[1][row][w][0] = sum1;  part[1][row][w][1] = ssq1;
        }
        __syncthreads();
        float mu[2], rs[2];
        #pragma unroll
        for (int ht = 0; ht < 2; ++ht) {
            float S = 0.f, Q = 0.f;
            #pragma unroll
            for (int ww = 0; ww < 4; ++ww) {
                S += part[ht][row][ww][0];
                Q += part[ht][row][ww][1];
            }
            const float invn = 1.f / (float)DFF;
            mu[ht] = S * invn;
            float var = Q * invn - mu[ht] * mu[ht];
            rs[ht] = rsqrtf(var + 1e-5f);
        }
        // -------- pass 2: normalize fp32 regs, pack bf16, single LDS write --------
        #pragma unroll
        for (int mt = 0; mt < 8; ++mt) {
            const int nb = w * 128 + mt * 16 + quad * 4;
            const float4v g4  = *(const float4v*)(gamma + nb);
            const float4v be4 = *(const float4v*)(beta + nb);
            #pragma unroll
            for (int ht = 0; ht < 2; ++ht) {
                float o[4];
                #pragma unroll
                for (int r = 0; r < 4; ++r) {
                    float tg = rs[ht] * g4[r];
                    o[r] = acc[mt][ht][r] * tg + (be4[r] - mu[ht] * tg);
                }
                uint2 p;
                p.x = pk_bf16(o[0], o[1]);
                p.y = pk_bf16(o[2], o[3]);
                *(uint2*)&Hsm[ht * 16 + row][nb] = p;
            }
        }
        __syncthreads();

        // -------- GEMM2 (A=Hs [hop][k] LDS, B=w2t [tt][k] global) --------
        {
            float4v acc2[2];
            acc2[0] = (float4v){0.f,0.f,0.f,0.f};
            acc2[1] = (float4v){0.f,0.f,0.f,0.f};
            #pragma unroll
            for (int ks = 0; ks < 16; ++ks) {
                const int k0 = ks * 32 + quad * 8;
                short8 bfr = *(const short8*)(w2t + (size_t)(w * 16 + row) * DFF + k0);
                #pragma unroll
                for (int mt = 0; mt < 2; ++mt) {
                    short8 afr = *(const short8*)&Hsm[mt * 16 + row][k0];
                    acc2[mt] = __builtin_amdgcn_mfma_f32_16x16x32_bf16(
                        afr, bfr, acc2[mt], 0, 0, 0);
                }
            }
            const float bb = b2[w * 16 + row];
            #pragma unroll
            for (int mt = 0; mt < 2; ++mt) {
                #pragma unroll
                for (int r = 0; r < 4; ++r) {
                    int hop = hop0 + mt * 16 + quad * 4 + r;
                    if (hop < H)
                        out[(size_t)hop * TTW + w * 16 + row] = acc2[mt][r] + bb;
                }
            }
        }
        if (COOP) __syncthreads();   // protect Apool/Hsm reuse by next iteration
    }
}

extern "C" void kernel_launch(void* const* d_in, const int* in_sizes, int n_in,
                              void* d_out, int out_size, void* d_ws, size_t ws_size,
                              hipStream_t stream) {
    const float* hf    = (const float*)d_in[0];
    const float* w_q   = (const float*)d_in[1];
    const float* W1    = (const float*)d_in[2];
    const float* b1    = (const float*)d_in[3];
    const float* gamma = (const float*)d_in[4];
    const float* beta  = (const float*)d_in[5];
    const float* W2    = (const float*)d_in[6];
    const float* b2    = (const float*)d_in[7];
    const int* pi      = (const int*)d_in[8];
    const int* stats   = (const int*)d_in[9];
    const int* po      = (const int*)d_in[10];
    float* out         = (float*)d_out;

    int n_hf = in_sizes[0];           // N_NODES*128
    int H    = in_sizes[10];
    int ntiles = (H + TILE_H - 1) / TILE_H;

    // ws layout
    char* ws = (char*)d_ws;
    unsigned short* w1t = (unsigned short*)ws;                       // 128KB
    unsigned short* w2t = (unsigned short*)(ws + 131072);            // 64KB
    unsigned short* hf2 = (unsigned short*)(ws + 196608);            // n_hf*2

    // --- capture-safe, deterministic queries -> same decision every call ---
    int coop_attr = 0, dev = 0;
    hipGetDevice(&dev);
    hipDeviceGetAttribute(&coop_attr, hipDeviceAttributeCooperativeLaunch, dev);
    int maxb = 0;
    hipError_t oe = hipOccupancyMaxActiveBlocksPerMultiprocessor(
        &maxb, fused_t<true>, 256, 0);

    if (coop_attr && oe == hipSuccess && maxb >= 2) {
        const int maxgrid = 256 * maxb;              // valid by driver's own count
        // equal tiles per block: no tail straggler (3125 tiles, maxb=3 -> 625x5)
        int tpb  = (ntiles + maxgrid - 1) / maxgrid;
        int grid = (ntiles + tpb - 1) / tpb;
        if (grid >= 97) {                            // phase 0 needs 96 transpose blocks
            void* args[] = {
                (void*)&hf, (void*)&w_q, (void*)&pi, (void*)&stats, (void*)&po,
                (void*)&W1, (void*)&W2, (void*)&b1, (void*)&gamma, (void*)&beta,
                (void*)&b2, (void*)&hf2, (void*)&w1t, (void*)&w2t, (void*)&out,
                (void*)&H, (void*)&ntiles, (void*)&n_hf
            };
            hipError_t le = hipLaunchCooperativeKernel((const void*)&fused_t<true>,
                                                       dim3(grid), dim3(256),
                                                       args, 0, stream);
            if (le == hipSuccess) return;
        }
        // fall through to the proven 2-kernel path on any disqualification
    }

    const int B_HF = (n_hf + 2047) / 2048;   // 8 elems/thread
    hipLaunchKernelGGL(prep_k, dim3(B_HF + 96), dim3(256), 0, stream,
                       hf, W1, W2, hf2, w1t, w2t, n_hf, B_HF);
    hipLaunchKernelGGL((fused_t<false>), dim3(ntiles), dim3(256), 0, stream,
                       hf, w_q, pi, stats, po, W1, W2, b1, gamma, beta, b2,
                       hf2, w1t, w2t, out, H, ntiles, n_hf);
}

// Round 13
// 237.492 us; speedup vs baseline: 3.0997x; 3.0997x over previous
//
#include <hip/hip_runtime.h>
#include <hip/hip_bf16.h>
#include <math.h>

#define DIM 128
#define DFF 512
#define TTW 64
#define NPI 8
#define NTOK 9
#define TILE_H 32
#define THREADS 512

typedef __attribute__((ext_vector_type(8))) short short8;
typedef __attribute__((ext_vector_type(4))) float float4v;

__device__ __forceinline__ float bf16lo_f32(unsigned u) {
    union { unsigned u; float f; } v; v.u = u << 16;
    return v.f;
}
__device__ __forceinline__ float bf16hi_f32(unsigned u) {
    union { unsigned u; float f; } v; v.u = u & 0xffff0000u;
    return v.f;
}
__device__ __forceinline__ unsigned pk_bf16(float a, float b) {  // -> a | b<<16
    __hip_bfloat162 h = __float22bfloat162_rn(float2{a, b});
    union { __hip_bfloat162 h; unsigned u; } cv; cv.h = h;
    return cv.u;
}

// ============ prep: hf->bf16 (8 elems/thread) + W1/W2 transposes ============
__global__ __launch_bounds__(256)
void prep_k(const float* __restrict__ hf, const float* __restrict__ W1,
            const float* __restrict__ W2,
            unsigned short* __restrict__ hf2, unsigned short* __restrict__ w1t,
            unsigned short* __restrict__ w2t,
            int n_hf, int B_HF)
{
    __shared__ float tile[32][33];
    const int b = blockIdx.x, t = threadIdx.x;
    if (b < B_HF) {
        int i = (b * 256 + t) * 8;
        if (i < n_hf) {
            float4v v0 = *(const float4v*)(hf + i);
            float4v v1 = *(const float4v*)(hf + i + 4);
            uint4 o;
            o.x = pk_bf16(v0[0], v0[1]);
            o.y = pk_bf16(v0[2], v0[3]);
            o.z = pk_bf16(v1[0], v1[1]);
            o.w = pk_bf16(v1[2], v1[3]);
            *(uint4*)(hf2 + i) = o;
        }
    } else if (b < B_HF + 64) {
        const int tb = b - B_HF;            // W1 [128][512] -> w1t bf16 [512][128]
        const int r0 = (tb & 3) * 32, c0 = (tb >> 2) * 32;
        const int ty = t >> 3, tx = t & 7;
        *(float4v*)&tile[ty][tx * 4] = *(const float4v*)(W1 + (r0 + ty) * DFF + c0 + tx * 4);
        __syncthreads();
        uint2 o;
        o.x = pk_bf16(tile[tx * 4 + 0][ty], tile[tx * 4 + 1][ty]);
        o.y = pk_bf16(tile[tx * 4 + 2][ty], tile[tx * 4 + 3][ty]);
        *(uint2*)(w1t + (c0 + ty) * DIM + r0 + tx * 4) = o;
    } else {
        const int tb = b - B_HF - 64;       // W2 [512][64] -> w2t bf16 [64][512]
        const int r0 = (tb & 15) * 32, c0 = (tb >> 4) * 32;
        const int ty = t >> 3, tx = t & 7;
        *(float4v*)&tile[ty][tx * 4] = *(const float4v*)(W2 + (r0 + ty) * TTW + c0 + tx * 4);
        __syncthreads();
        uint2 o;
        o.x = pk_bf16(tile[tx * 4 + 0][ty], tile[tx * 4 + 1][ty]);
        o.y = pk_bf16(tile[tx * 4 + 2][ty], tile[tx * 4 + 3][ty]);
        *(uint2*)(w2t + (c0 + ty) * DFF + r0 + tx * 4) = o;
    }
}

// ===== fused (512-thread / 8-wave blocks): gather+pool -> GEMM1 -> reg-LN -> GEMM2 =====
// NO cooperative launch (R10/R12: coop wrapper alone cost ~580 MB HBM traffic, 3.4x).
// __launch_bounds__(512,4): 128-reg cap, 2 blocks/CU = 16 waves/CU (vs 9.6 at 256thr).
// Tighter bounds spill the fp32 accumulators (R7 lesson).
__global__ __launch_bounds__(THREADS, 4)
void fused_k(const unsigned short* __restrict__ hf2,
             const float* __restrict__ w_q,
             const int* __restrict__ pi,
             const int* __restrict__ stats,
             const int* __restrict__ po,
             const unsigned short* __restrict__ w1t,     // bf16 [512][128]
             const float* __restrict__ b1,
             const float* __restrict__ gamma,
             const float* __restrict__ beta,
             const unsigned short* __restrict__ w2t,     // bf16 [64][512]
             const float* __restrict__ b2,
             float* __restrict__ out,
             int H)
{
    __shared__ __align__(16) unsigned short Apool[TILE_H][DIM + 8];   // 8704 B
    __shared__ __align__(16) unsigned short Hsm[TILE_H][DFF + 8];     // 33280 B
    __shared__ float part[2][16][8][2];                 // [ht][row][wave][sum,ssq]

    const int t    = threadIdx.x;
    const int lane = t & 63;
    const int w    = t >> 6;          // wave 0..7
    const int row  = lane & 15;
    const int quad = lane >> 4;
    const int hop0 = blockIdx.x * TILE_H;

    // -------- Phase 1: gather + masked attention pooling (32 lanes/hop, 2 iters) --------
    {
        const int g = t >> 5, l = t & 31;       // g 0..15; lane l owns dims 4l..4l+3
        const float4v wq4 = *(const float4v*)(w_q + l * 4);

        int idxs[2][NTOK];
        unsigned vm[2];
        #pragma unroll
        for (int it = 0; it < 2; ++it) {
            int hop = hop0 + g + it * 16;
            if (hop >= H) hop = H - 1;          // clamp; out stores are guarded
            int4 p0 = *(const int4*)(pi + hop * NPI);
            int4 p1 = *(const int4*)(pi + hop * NPI + 4);
            int4 s0 = *(const int4*)(stats + hop * NPI);
            int4 s1 = *(const int4*)(stats + hop * NPI + 4);
            idxs[it][0] = p0.x; idxs[it][1] = p0.y;
            idxs[it][2] = p0.z; idxs[it][3] = p0.w;
            idxs[it][4] = p1.x; idxs[it][5] = p1.y;
            idxs[it][6] = p1.z; idxs[it][7] = p1.w;
            idxs[it][8] = po[hop];
            vm[it] = (s0.x != -1 ? 1u   : 0u) | (s0.y != -1 ? 2u   : 0u)
                   | (s0.z != -1 ? 4u   : 0u) | (s0.w != -1 ? 8u   : 0u)
                   | (s1.x != -1 ? 16u  : 0u) | (s1.y != -1 ? 32u  : 0u)
                   | (s1.z != -1 ? 64u  : 0u) | (s1.w != -1 ? 128u : 0u)
                   | 256u;                      // PO always valid
        }
        uint2 tu[2][NTOK];                      // 36 VGPRs; hoisted so all 18 loads overlap
        #pragma unroll
        for (int it = 0; it < 2; ++it)
            #pragma unroll
            for (int p = 0; p < NTOK; ++p)
                tu[it][p] = *(const uint2*)(hf2 + (size_t)idxs[it][p] * DIM + l * 4);

        #pragma unroll
        for (int it = 0; it < 2; ++it) {
            const int hl = g + it * 16;
            float tok[NTOK][4];
            #pragma unroll
            for (int p = 0; p < NTOK; ++p) {
                tok[p][0] = bf16lo_f32(tu[it][p].x);
                tok[p][1] = bf16hi_f32(tu[it][p].x);
                tok[p][2] = bf16lo_f32(tu[it][p].y);
                tok[p][3] = bf16hi_f32(tu[it][p].y);
            }
            float sc[NTOK];
            #pragma unroll
            for (int p = 0; p < NTOK; ++p)
                sc[p] = tok[p][0]*wq4[0] + tok[p][1]*wq4[1]
                      + tok[p][2]*wq4[2] + tok[p][3]*wq4[3];
            #pragma unroll
            for (int m = 1; m < 32; m <<= 1) {
                #pragma unroll
                for (int p = 0; p < NTOK; ++p) sc[p] += __shfl_xor(sc[p], m);
            }
            const float isd = 0.08838834764831845f;   // 1/sqrt(128)
            float mx = -1e30f;
            #pragma unroll
            for (int p = 0; p < NTOK; ++p) {
                sc[p] = ((vm[it] >> p) & 1u) ? sc[p] * isd : -1e30f;
                mx = fmaxf(mx, sc[p]);
            }
            float se = 0.f;
            #pragma unroll
            for (int p = 0; p < NTOK; ++p) { sc[p] = __expf(sc[p] - mx); se += sc[p]; }
            const float inv = 1.f / se;
            float a0=0.f, a1=0.f, a2=0.f, a3=0.f;
            #pragma unroll
            for (int p = 0; p < NTOK; ++p) {
                float a = sc[p] * inv;
                a0 += a * tok[p][0]; a1 += a * tok[p][1];
                a2 += a * tok[p][2]; a3 += a * tok[p][3];
            }
            uint2 o;
            o.x = pk_bf16(a0, a1);
            o.y = pk_bf16(a2, a3);
            *(uint2*)&Apool[hl][l * 4] = o;
        }
    }
    __syncthreads();

    // -------- GEMM1: wave w owns out-dims [w*64, w*64+64): 4 mt x 2 hop-tiles --------
    float4v acc[4][2];
    #pragma unroll
    for (int mt = 0; mt < 4; ++mt) {
        acc[mt][0] = (float4v){0.f, 0.f, 0.f, 0.f};
        acc[mt][1] = (float4v){0.f, 0.f, 0.f, 0.f};
    }
    {
        short8 bfr[2][4];
        #pragma unroll
        for (int ks = 0; ks < 4; ++ks) {
            const int k0 = ks * 32 + quad * 8;
            #pragma unroll
            for (int ht = 0; ht < 2; ++ht)
                bfr[ht][ks] = *(const short8*)&Apool[ht * 16 + row][k0];
        }
        #pragma unroll
        for (int mt = 0; mt < 4; ++mt) {
            const unsigned short* wrow = w1t + (size_t)(w * 64 + mt * 16 + row) * DIM;
            #pragma unroll
            for (int ks = 0; ks < 4; ++ks) {
                short8 afr = *(const short8*)(wrow + ks * 32 + quad * 8);
                acc[mt][0] = __builtin_amdgcn_mfma_f32_16x16x32_bf16(afr, bfr[0][ks], acc[mt][0], 0, 0, 0);
                acc[mt][1] = __builtin_amdgcn_mfma_f32_16x16x32_bf16(afr, bfr[1][ks], acc[mt][1], 0, 0, 0);
            }
        }
    }
    // -------- pass 1: bias + ReLU in registers, LN stats --------
    float sum0 = 0.f, ssq0 = 0.f, sum1 = 0.f, ssq1 = 0.f;
    #pragma unroll
    for (int mt = 0; mt < 4; ++mt) {
        const int nb = w * 64 + mt * 16 + quad * 4;
        const float4v bias = *(const float4v*)(b1 + nb);
        #pragma unroll
        for (int r = 0; r < 4; ++r) {
            float v0 = fmaxf(acc[mt][0][r] + bias[r], 0.f);
            float v1 = fmaxf(acc[mt][1][r] + bias[r], 0.f);
            acc[mt][0][r] = v0;  sum0 += v0;  ssq0 += v0 * v0;
            acc[mt][1][r] = v1;  sum1 += v1;  ssq1 += v1 * v1;
        }
    }
    #pragma unroll
    for (int m = 16; m <= 32; m <<= 1) {       // reduce across the 4 quads
        sum0 += __shfl_xor(sum0, m);  ssq0 += __shfl_xor(ssq0, m);
        sum1 += __shfl_xor(sum1, m);  ssq1 += __shfl_xor(ssq1, m);
    }
    if (lane < 16) {
        part[0][row][w][0] = sum0;  part[0][row][w][1] = ssq0;
        part[1][row][w][0] = sum1;  part[1][row][w][1] = ssq1;
    }
    __syncthreads();
    float mu[2], rs[2];
    #pragma unroll
    for (int ht = 0; ht < 2; ++ht) {
        float S = 0.f, Q = 0.f;
        #pragma unroll
        for (int ww = 0; ww < 8; ++ww) {
            S += part[ht][row][ww][0];
            Q += part[ht][row][ww][1];
        }
        const float invn = 1.f / (float)DFF;
        mu[ht] = S * invn;
        float var = Q * invn - mu[ht] * mu[ht];
        rs[ht] = rsqrtf(var + 1e-5f);
    }
    // -------- pass 2: normalize fp32 regs, pack bf16, single LDS write --------
    #pragma unroll
    for (int mt = 0; mt < 4; ++mt) {
        const int nb = w * 64 + mt * 16 + quad * 4;
        const float4v g4  = *(const float4v*)(gamma + nb);
        const float4v be4 = *(const float4v*)(beta + nb);
        #pragma unroll
        for (int ht = 0; ht < 2; ++ht) {
            float o[4];
            #pragma unroll
            for (int r = 0; r < 4; ++r) {
                float tg = rs[ht] * g4[r];
                o[r] = acc[mt][ht][r] * tg + (be4[r] - mu[ht] * tg);
            }
            uint2 p;
            p.x = pk_bf16(o[0], o[1]);
            p.y = pk_bf16(o[2], o[3]);
            *(uint2*)&Hsm[ht * 16 + row][nb] = p;
        }
    }
    __syncthreads();

    // -------- GEMM2: wave task = (hop-half, tt-quarter); 16 MFMA per wave --------
    {
        const int mtile = w >> 2;          // 0..1: hops mtile*16..+15
        const int ttile = w & 3;           // 0..3: tt cols ttile*16..+15
        float4v acc2 = (float4v){0.f,0.f,0.f,0.f};
        #pragma unroll
        for (int ks = 0; ks < 16; ++ks) {
            const int k0 = ks * 32 + quad * 8;
            short8 bfr = *(const short8*)(w2t + (size_t)(ttile * 16 + row) * DFF + k0);
            short8 afr = *(const short8*)&Hsm[mtile * 16 + row][k0];
            acc2 = __builtin_amdgcn_mfma_f32_16x16x32_bf16(afr, bfr, acc2, 0, 0, 0);
        }
        const float bb = b2[ttile * 16 + row];
        #pragma unroll
        for (int r = 0; r < 4; ++r) {
            int hop = hop0 + mtile * 16 + quad * 4 + r;
            if (hop < H)
                out[(size_t)hop * TTW + ttile * 16 + row] = acc2[r] + bb;
        }
    }
}

extern "C" void kernel_launch(void* const* d_in, const int* in_sizes, int n_in,
                              void* d_out, int out_size, void* d_ws, size_t ws_size,
                              hipStream_t stream) {
    const float* hf    = (const float*)d_in[0];
    const float* w_q   = (const float*)d_in[1];
    const float* W1    = (const float*)d_in[2];
    const float* b1    = (const float*)d_in[3];
    const float* gamma = (const float*)d_in[4];
    const float* beta  = (const float*)d_in[5];
    const float* W2    = (const float*)d_in[6];
    const float* b2    = (const float*)d_in[7];
    const int* pi      = (const int*)d_in[8];
    const int* stats   = (const int*)d_in[9];
    const int* po      = (const int*)d_in[10];
    float* out         = (float*)d_out;

    const int n_hf = in_sizes[0];           // N_NODES*128
    const int H    = in_sizes[10];
    const int ntiles = (H + TILE_H - 1) / TILE_H;

    // ws layout
    char* ws = (char*)d_ws;
    unsigned short* w1t = (unsigned short*)ws;                       // 128KB
    unsigned short* w2t = (unsigned short*)(ws + 131072);            // 64KB
    unsigned short* hf2 = (unsigned short*)(ws + 196608);            // n_hf*2

    const int B_HF = (n_hf + 2047) / 2048;   // 8 elems/thread
    hipLaunchKernelGGL(prep_k, dim3(B_HF + 96), dim3(256), 0, stream,
                       hf, W1, W2, hf2, w1t, w2t, n_hf, B_HF);
    hipLaunchKernelGGL(fused_k, dim3(ntiles), dim3(THREADS), 0, stream,
                       hf2, w_q, pi, stats, po, w1t, b1, gamma, beta, w2t, b2, out, H);
}

// Round 14
// 231.573 us; speedup vs baseline: 3.1790x; 1.0256x over previous
//
#include <hip/hip_runtime.h>
#include <hip/hip_bf16.h>
#include <math.h>

#define DIM 128
#define DFF 512
#define TTW 64
#define NPI 8
#define NTOK 9
#define TILE_H 32

typedef __attribute__((ext_vector_type(8))) short short8;
typedef __attribute__((ext_vector_type(4))) float float4v;

__device__ __forceinline__ unsigned pk_bf16(float a, float b) {  // -> a | b<<16
    __hip_bfloat162 h = __float22bfloat162_rn(float2{a, b});
    union { __hip_bfloat162 h; unsigned u; } cv; cv.h = h;
    return cv.u;
}

// ============ prep (tiny: 96 blocks): W1/W2 -> bf16 transposed ============
__global__ __launch_bounds__(256)
void prep_k(const float* __restrict__ W1, const float* __restrict__ W2,
            unsigned short* __restrict__ w1t, unsigned short* __restrict__ w2t)
{
    __shared__ float tile[32][33];
    const int b = blockIdx.x, t = threadIdx.x;
    if (b < 64) {
        const int tb = b;                   // W1 [128][512] -> w1t bf16 [512][128]
        const int r0 = (tb & 3) * 32, c0 = (tb >> 2) * 32;
        const int ty = t >> 3, tx = t & 7;
        *(float4v*)&tile[ty][tx * 4] = *(const float4v*)(W1 + (r0 + ty) * DFF + c0 + tx * 4);
        __syncthreads();
        uint2 o;
        o.x = pk_bf16(tile[tx * 4 + 0][ty], tile[tx * 4 + 1][ty]);
        o.y = pk_bf16(tile[tx * 4 + 2][ty], tile[tx * 4 + 3][ty]);
        *(uint2*)(w1t + (c0 + ty) * DIM + r0 + tx * 4) = o;
    } else {
        const int tb = b - 64;              // W2 [512][64] -> w2t bf16 [64][512]
        const int r0 = (tb & 15) * 32, c0 = (tb >> 4) * 32;
        const int ty = t >> 3, tx = t & 7;
        *(float4v*)&tile[ty][tx * 4] = *(const float4v*)(W2 + (r0 + ty) * TTW + c0 + tx * 4);
        __syncthreads();
        uint2 o;
        o.x = pk_bf16(tile[tx * 4 + 0][ty], tile[tx * 4 + 1][ty]);
        o.y = pk_bf16(tile[tx * 4 + 2][ty], tile[tx * 4 + 3][ty]);
        *(uint2*)(w2t + (c0 + ty) * DFF + r0 + tx * 4) = o;
    }
}

// ===== fused: fp32 gather+pool -> GEMM1 -> reg-LN -> GEMM2 (R11-best body) =====
// __launch_bounds__(256,3): tighter bounds spill the fp32 accumulators
// (R7: WRITE_SIZE 37->214 MB = scratch). 256-thread blocks (R13's 512 regressed).
__global__ __launch_bounds__(256, 3)
void fused_k(const float* __restrict__ hf,              // fp32 node features (no prep!)
             const float* __restrict__ w_q,
             const int* __restrict__ pi,
             const int* __restrict__ stats,
             const int* __restrict__ po,
             const unsigned short* __restrict__ w1t,     // bf16 [512][128]
             const float* __restrict__ b1,
             const float* __restrict__ gamma,
             const float* __restrict__ beta,
             const unsigned short* __restrict__ w2t,     // bf16 [64][512]
             const float* __restrict__ b2,
             float* __restrict__ out,
             int H)
{
    __shared__ __align__(16) unsigned short Apool[TILE_H][DIM + 8];   // 8704 B
    __shared__ __align__(16) unsigned short Hsm[TILE_H][DFF + 8];     // 33280 B
    __shared__ float part[2][16][4][2];                 // [ht][row][wave][sum,ssq]

    const int t    = threadIdx.x;
    const int lane = t & 63;
    const int w    = t >> 6;
    const int row  = lane & 15;
    const int quad = lane >> 4;
    const int hop0 = blockIdx.x * TILE_H;

    // -------- Phase 1: fp32 gather + masked attention pooling (32 lanes/hop) --------
    {
        const int g = t >> 5, l = t & 31;       // lane l owns dims 4l..4l+3
        const float4v wq4 = *(const float4v*)(w_q + l * 4);
        #pragma unroll
        for (int it = 0; it < 4; ++it) {
            const int hl = g + it * 8;
            int hop = hop0 + hl;
            if (hop >= H) hop = H - 1;          // clamp; out stores are guarded
            int idx[NTOK];
            unsigned vm;
            {
                int4 p0 = *(const int4*)(pi + hop * NPI);
                int4 p1 = *(const int4*)(pi + hop * NPI + 4);
                int4 s0 = *(const int4*)(stats + hop * NPI);
                int4 s1 = *(const int4*)(stats + hop * NPI + 4);
                idx[0]=p0.x; idx[1]=p0.y; idx[2]=p0.z; idx[3]=p0.w;
                idx[4]=p1.x; idx[5]=p1.y; idx[6]=p1.z; idx[7]=p1.w;
                idx[8]=po[hop];
                vm = (s0.x != -1 ? 1u   : 0u) | (s0.y != -1 ? 2u   : 0u)
                   | (s0.z != -1 ? 4u   : 0u) | (s0.w != -1 ? 8u   : 0u)
                   | (s1.x != -1 ? 16u  : 0u) | (s1.y != -1 ? 32u  : 0u)
                   | (s1.z != -1 ? 64u  : 0u) | (s1.w != -1 ? 128u : 0u)
                   | 256u;                      // PO always valid
            }
            float4v tok[NTOK];                  // 36 VGPRs; 9 loads issued together
            #pragma unroll
            for (int p = 0; p < NTOK; ++p)
                tok[p] = *(const float4v*)(hf + (size_t)idx[p] * DIM + l * 4);

            float sc[NTOK];
            #pragma unroll
            for (int p = 0; p < NTOK; ++p)
                sc[p] = tok[p][0]*wq4[0] + tok[p][1]*wq4[1]
                      + tok[p][2]*wq4[2] + tok[p][3]*wq4[3];
            #pragma unroll
            for (int m = 1; m < 32; m <<= 1) {
                #pragma unroll
                for (int p = 0; p < NTOK; ++p) sc[p] += __shfl_xor(sc[p], m);
            }
            const float isd = 0.08838834764831845f;   // 1/sqrt(128)
            float mx = -1e30f;
            #pragma unroll
            for (int p = 0; p < NTOK; ++p) {
                sc[p] = ((vm >> p) & 1u) ? sc[p] * isd : -1e30f;
                mx = fmaxf(mx, sc[p]);
            }
            float se = 0.f;
            #pragma unroll
            for (int p = 0; p < NTOK; ++p) { sc[p] = __expf(sc[p] - mx); se += sc[p]; }
            const float inv = 1.f / se;
            float a0=0.f, a1=0.f, a2=0.f, a3=0.f;
            #pragma unroll
            for (int p = 0; p < NTOK; ++p) {
                float a = sc[p] * inv;
                a0 += a * tok[p][0]; a1 += a * tok[p][1];
                a2 += a * tok[p][2]; a3 += a * tok[p][3];
            }
            uint2 o;
            o.x = pk_bf16(a0, a1);
            o.y = pk_bf16(a2, a3);
            *(uint2*)&Apool[hl][l * 4] = o;
        }
    }
    __syncthreads();

    // -------- GEMM1: A=W1T rows (out-dims), B=Apool^T (hops); all acc live --------
    float4v acc[8][2];
    #pragma unroll
    for (int mt = 0; mt < 8; ++mt) {
        acc[mt][0] = (float4v){0.f, 0.f, 0.f, 0.f};
        acc[mt][1] = (float4v){0.f, 0.f, 0.f, 0.f};
    }
    {
        short8 bfr[2][4];
        #pragma unroll
        for (int ks = 0; ks < 4; ++ks) {
            const int k0 = ks * 32 + quad * 8;
            #pragma unroll
            for (int ht = 0; ht < 2; ++ht)
                bfr[ht][ks] = *(const short8*)&Apool[ht * 16 + row][k0];
        }
        #pragma unroll
        for (int mt = 0; mt < 8; ++mt) {
            const unsigned short* wrow = w1t + (size_t)(w * 128 + mt * 16 + row) * DIM;
            #pragma unroll
            for (int ks = 0; ks < 4; ++ks) {
                short8 afr = *(const short8*)(wrow + ks * 32 + quad * 8);
                acc[mt][0] = __builtin_amdgcn_mfma_f32_16x16x32_bf16(afr, bfr[0][ks], acc[mt][0], 0, 0, 0);
                acc[mt][1] = __builtin_amdgcn_mfma_f32_16x16x32_bf16(afr, bfr[1][ks], acc[mt][1], 0, 0, 0);
            }
        }
    }
    // -------- pass 1: bias + ReLU in registers, LN stats --------
    float sum0 = 0.f, ssq0 = 0.f, sum1 = 0.f, ssq1 = 0.f;
    #pragma unroll
    for (int mt = 0; mt < 8; ++mt) {
        const int nb = w * 128 + mt * 16 + quad * 4;
        const float4v bias = *(const float4v*)(b1 + nb);
        #pragma unroll
        for (int r = 0; r < 4; ++r) {
            float v0 = fmaxf(acc[mt][0][r] + bias[r], 0.f);
            float v1 = fmaxf(acc[mt][1][r] + bias[r], 0.f);
            acc[mt][0][r] = v0;  sum0 += v0;  ssq0 += v0 * v0;
            acc[mt][1][r] = v1;  sum1 += v1;  ssq1 += v1 * v1;
        }
    }
    #pragma unroll
    for (int m = 16; m <= 32; m <<= 1) {       // reduce across the 4 quads
        sum0 += __shfl_xor(sum0, m);  ssq0 += __shfl_xor(ssq0, m);
        sum1 += __shfl_xor(sum1, m);  ssq1 += __shfl_xor(ssq1, m);
    }
    if (lane < 16) {
        part[0][row][w][0] = sum0;  part[0][row][w][1] = ssq0;
        part[1][row][w][0] = sum1;  part[1][row][w][1] = ssq1;
    }
    __syncthreads();
    float mu[2], rs[2];
    #pragma unroll
    for (int ht = 0; ht < 2; ++ht) {
        float S = 0.f, Q = 0.f;
        #pragma unroll
        for (int ww = 0; ww < 4; ++ww) {
            S += part[ht][row][ww][0];
            Q += part[ht][row][ww][1];
        }
        const float invn = 1.f / (float)DFF;
        mu[ht] = S * invn;
        float var = Q * invn - mu[ht] * mu[ht];
        rs[ht] = rsqrtf(var + 1e-5f);
    }
    // -------- pass 2: normalize fp32 regs, pack bf16, single LDS write --------
    #pragma unroll
    for (int mt = 0; mt < 8; ++mt) {
        const int nb = w * 128 + mt * 16 + quad * 4;
        const float4v g4  = *(const float4v*)(gamma + nb);
        const float4v be4 = *(const float4v*)(beta + nb);
        #pragma unroll
        for (int ht = 0; ht < 2; ++ht) {
            float o[4];
            #pragma unroll
            for (int r = 0; r < 4; ++r) {
                float tg = rs[ht] * g4[r];
                o[r] = acc[mt][ht][r] * tg + (be4[r] - mu[ht] * tg);
            }
            uint2 p;
            p.x = pk_bf16(o[0], o[1]);
            p.y = pk_bf16(o[2], o[3]);
            *(uint2*)&Hsm[ht * 16 + row][nb] = p;
        }
    }
    __syncthreads();

    // -------- GEMM2 (A=Hs [hop][k] LDS, B=w2t [tt][k] global) --------
    {
        float4v acc2[2];
        acc2[0] = (float4v){0.f,0.f,0.f,0.f};
        acc2[1] = (float4v){0.f,0.f,0.f,0.f};
        #pragma unroll
        for (int ks = 0; ks < 16; ++ks) {
            const int k0 = ks * 32 + quad * 8;
            short8 bfr = *(const short8*)(w2t + (size_t)(w * 16 + row) * DFF + k0);
            #pragma unroll
            for (int mt = 0; mt < 2; ++mt) {
                short8 afr = *(const short8*)&Hsm[mt * 16 + row][k0];
                acc2[mt] = __builtin_amdgcn_mfma_f32_16x16x32_bf16(
                    afr, bfr, acc2[mt], 0, 0, 0);
            }
        }
        const float bb = b2[w * 16 + row];
        #pragma unroll
        for (int mt = 0; mt < 2; ++mt) {
            #pragma unroll
            for (int r = 0; r < 4; ++r) {
                int hop = hop0 + mt * 16 + quad * 4 + r;
                if (hop < H)
                    out[(size_t)hop * TTW + w * 16 + row] = acc2[mt][r] + bb;
            }
        }
    }
}

extern "C" void kernel_launch(void* const* d_in, const int* in_sizes, int n_in,
                              void* d_out, int out_size, void* d_ws, size_t ws_size,
                              hipStream_t stream) {
    const float* hf    = (const float*)d_in[0];
    const float* w_q   = (const float*)d_in[1];
    const float* W1    = (const float*)d_in[2];
    const float* b1    = (const float*)d_in[3];
    const float* gamma = (const float*)d_in[4];
    const float* beta  = (const float*)d_in[5];
    const float* W2    = (const float*)d_in[6];
    const float* b2    = (const float*)d_in[7];
    const int* pi      = (const int*)d_in[8];
    const int* stats   = (const int*)d_in[9];
    const int* po      = (const int*)d_in[10];
    float* out         = (float*)d_out;

    const int H = in_sizes[10];
    const int ntiles = (H + TILE_H - 1) / TILE_H;

    // ws layout
    char* ws = (char*)d_ws;
    unsigned short* w1t = (unsigned short*)ws;                       // 128KB
    unsigned short* w2t = (unsigned short*)(ws + 131072);            // 64KB

    hipLaunchKernelGGL(prep_k, dim3(96), dim3(256), 0, stream, W1, W2, w1t, w2t);
    hipLaunchKernelGGL(fused_k, dim3(ntiles), dim3(256), 0, stream,
                       hf, w_q, pi, stats, po, w1t, b1, gamma, beta, w2t, b2, out, H);
}

// Round 15
// 207.423 us; speedup vs baseline: 3.5491x; 1.1164x over previous
//
#include <hip/hip_runtime.h>
#include <hip/hip_bf16.h>
#include <math.h>

#define DIM 128
#define DFF 512
#define TTW 64
#define NPI 8
#define NTOK 9
#define TILE_H 32

typedef __attribute__((ext_vector_type(8))) short short8;
typedef __attribute__((ext_vector_type(4))) float float4v;

__device__ __forceinline__ float bf16lo_f32(unsigned u) {
    union { unsigned u; float f; } v; v.u = u << 16;
    return v.f;
}
__device__ __forceinline__ float bf16hi_f32(unsigned u) {
    union { unsigned u; float f; } v; v.u = u & 0xffff0000u;
    return v.f;
}
__device__ __forceinline__ unsigned pk_bf16(float a, float b) {  // -> a | b<<16
    __hip_bfloat162 h = __float22bfloat162_rn(float2{a, b});
    union { __hip_bfloat162 h; unsigned u; } cv; cv.h = h;
    return cv.u;
}

// ============ prep: hf->bf16 (8 elems/thread) + W1/W2 transposes ============
__global__ __launch_bounds__(256)
void prep_k(const float* __restrict__ hf, const float* __restrict__ W1,
            const float* __restrict__ W2,
            unsigned short* __restrict__ hf2, unsigned short* __restrict__ w1t,
            unsigned short* __restrict__ w2t,
            int n_hf, int B_HF)
{
    __shared__ float tile[32][33];
    const int b = blockIdx.x, t = threadIdx.x;
    if (b < B_HF) {
        int i = (b * 256 + t) * 8;
        if (i < n_hf) {
            float4v v0 = *(const float4v*)(hf + i);
            float4v v1 = *(const float4v*)(hf + i + 4);
            uint4 o;
            o.x = pk_bf16(v0[0], v0[1]);
            o.y = pk_bf16(v0[2], v0[3]);
            o.z = pk_bf16(v1[0], v1[1]);
            o.w = pk_bf16(v1[2], v1[3]);
            *(uint4*)(hf2 + i) = o;
        }
    } else if (b < B_HF + 64) {
        const int tb = b - B_HF;            // W1 [128][512] -> w1t bf16 [512][128]
        const int r0 = (tb & 3) * 32, c0 = (tb >> 2) * 32;
        const int ty = t >> 3, tx = t & 7;
        *(float4v*)&tile[ty][tx * 4] = *(const float4v*)(W1 + (r0 + ty) * DFF + c0 + tx * 4);
        __syncthreads();
        uint2 o;
        o.x = pk_bf16(tile[tx * 4 + 0][ty], tile[tx * 4 + 1][ty]);
        o.y = pk_bf16(tile[tx * 4 + 2][ty], tile[tx * 4 + 3][ty]);
        *(uint2*)(w1t + (c0 + ty) * DIM + r0 + tx * 4) = o;
    } else {
        const int tb = b - B_HF - 64;       // W2 [512][64] -> w2t bf16 [64][512]
        const int r0 = (tb & 15) * 32, c0 = (tb >> 4) * 32;
        const int ty = t >> 3, tx = t & 7;
        *(float4v*)&tile[ty][tx * 4] = *(const float4v*)(W2 + (r0 + ty) * TTW + c0 + tx * 4);
        __syncthreads();
        uint2 o;
        o.x = pk_bf16(tile[tx * 4 + 0][ty], tile[tx * 4 + 1][ty]);
        o.y = pk_bf16(tile[tx * 4 + 2][ty], tile[tx * 4 + 3][ty]);
        *(uint2*)(w2t + (c0 + ty) * DFF + r0 + tx * 4) = o;
    }
}

// ===== fused: bf16 gather + 16-lane/hop pooling -> GEMM1 -> reg-LN -> GEMM2 =====
// __launch_bounds__(256,3): tighter bounds spill the fp32 accumulators
// (R7: WRITE_SIZE 37->214 MB = scratch). bf16 hf2 gather is worth ~44 us vs fp32
// (R14: FETCH 90->199 MB, +44 us). 256-thread blocks (R13's 512 regressed).
__global__ __launch_bounds__(256, 3)
void fused_k(const unsigned short* __restrict__ hf2,    // bf16 node features
             const float* __restrict__ w_q,
             const int* __restrict__ pi,
             const int* __restrict__ stats,
             const int* __restrict__ po,
             const unsigned short* __restrict__ w1t,     // bf16 [512][128]
             const float* __restrict__ b1,
             const float* __restrict__ gamma,
             const float* __restrict__ beta,
             const unsigned short* __restrict__ w2t,     // bf16 [64][512]
             const float* __restrict__ b2,
             float* __restrict__ out,
             int H)
{
    __shared__ __align__(16) unsigned short Apool[TILE_H][DIM + 8];   // 8704 B
    __shared__ __align__(16) unsigned short Hsm[TILE_H][DFF + 8];     // 33280 B
    __shared__ float part[2][16][4][2];                 // [ht][row][wave][sum,ssq]

    const int t    = threadIdx.x;
    const int lane = t & 63;
    const int w    = t >> 6;
    const int row  = lane & 15;
    const int quad = lane >> 4;
    const int hop0 = blockIdx.x * TILE_H;

    // -------- Phase 1: gather + pooling, 16 lanes/hop (lane owns dims 8l..8l+7) --------
    // One uint4 = full 16 B/lane; 16 lanes = entire 256-B token row per instruction.
    // Softmax scalar chain + 4-level shuffle now run at half the lane redundancy of
    // the 32-lane layout (R11): ~108 fewer shuffle + ~54 fewer exp-chain ops/thread.
    {
        const int g = t >> 4, l = t & 15;
        float wq[8];
        {
            float4v a = *(const float4v*)(w_q + l * 8);
            float4v b = *(const float4v*)(w_q + l * 8 + 4);
            wq[0]=a[0]; wq[1]=a[1]; wq[2]=a[2]; wq[3]=a[3];
            wq[4]=b[0]; wq[5]=b[1]; wq[6]=b[2]; wq[7]=b[3];
        }
        #pragma unroll
        for (int it = 0; it < 2; ++it) {
            const int hl = g + it * 16;
            int hop = hop0 + hl;
            if (hop >= H) hop = H - 1;          // clamp; out stores are guarded
            int idx[NTOK];
            unsigned vm;
            {
                int4 p0 = *(const int4*)(pi + hop * NPI);
                int4 p1 = *(const int4*)(pi + hop * NPI + 4);
                int4 s0 = *(const int4*)(stats + hop * NPI);
                int4 s1 = *(const int4*)(stats + hop * NPI + 4);
                idx[0]=p0.x; idx[1]=p0.y; idx[2]=p0.z; idx[3]=p0.w;
                idx[4]=p1.x; idx[5]=p1.y; idx[6]=p1.z; idx[7]=p1.w;
                idx[8]=po[hop];
                vm = (s0.x != -1 ? 1u   : 0u) | (s0.y != -1 ? 2u   : 0u)
                   | (s0.z != -1 ? 4u   : 0u) | (s0.w != -1 ? 8u   : 0u)
                   | (s1.x != -1 ? 16u  : 0u) | (s1.y != -1 ? 32u  : 0u)
                   | (s1.z != -1 ? 64u  : 0u) | (s1.w != -1 ? 128u : 0u)
                   | 256u;                      // PO always valid
            }
            uint4 tu[NTOK];                     // 36 VGPRs; 9 full-row loads in flight
            #pragma unroll
            for (int p = 0; p < NTOK; ++p)
                tu[p] = *(const uint4*)(hf2 + (size_t)idx[p] * DIM + l * 8);

            float tok[NTOK][8];
            #pragma unroll
            for (int p = 0; p < NTOK; ++p) {
                tok[p][0] = bf16lo_f32(tu[p].x);  tok[p][1] = bf16hi_f32(tu[p].x);
                tok[p][2] = bf16lo_f32(tu[p].y);  tok[p][3] = bf16hi_f32(tu[p].y);
                tok[p][4] = bf16lo_f32(tu[p].z);  tok[p][5] = bf16hi_f32(tu[p].z);
                tok[p][6] = bf16lo_f32(tu[p].w);  tok[p][7] = bf16hi_f32(tu[p].w);
            }
            float sc[NTOK];
            #pragma unroll
            for (int p = 0; p < NTOK; ++p) {
                float s = 0.f;
                #pragma unroll
                for (int j = 0; j < 8; ++j) s += tok[p][j] * wq[j];
                sc[p] = s;
            }
            #pragma unroll
            for (int m = 1; m < 16; m <<= 1) {  // 4 levels, stays in 16-lane group
                #pragma unroll
                for (int p = 0; p < NTOK; ++p) sc[p] += __shfl_xor(sc[p], m);
            }
            const float isd = 0.08838834764831845f;   // 1/sqrt(128)
            float mx = -1e30f;
            #pragma unroll
            for (int p = 0; p < NTOK; ++p) {
                sc[p] = ((vm >> p) & 1u) ? sc[p] * isd : -1e30f;
                mx = fmaxf(mx, sc[p]);
            }
            float se = 0.f;
            #pragma unroll
            for (int p = 0; p < NTOK; ++p) { sc[p] = __expf(sc[p] - mx); se += sc[p]; }
            const float inv = 1.f / se;
            float a0=0,a1=0,a2=0,a3=0,a4=0,a5=0,a6=0,a7=0;
            #pragma unroll
            for (int p = 0; p < NTOK; ++p) {
                float a = sc[p] * inv;
                a0 += a * tok[p][0]; a1 += a * tok[p][1];
                a2 += a * tok[p][2]; a3 += a * tok[p][3];
                a4 += a * tok[p][4]; a5 += a * tok[p][5];
                a6 += a * tok[p][6]; a7 += a * tok[p][7];
            }
            uint4 o;
            o.x = pk_bf16(a0, a1);
            o.y = pk_bf16(a2, a3);
            o.z = pk_bf16(a4, a5);
            o.w = pk_bf16(a6, a7);
            *(uint4*)&Apool[hl][l * 8] = o;
        }
    }
    __syncthreads();

    // -------- GEMM1: A=W1T rows (out-dims), B=Apool^T (hops); all acc live --------
    float4v acc[8][2];
    #pragma unroll
    for (int mt = 0; mt < 8; ++mt) {
        acc[mt][0] = (float4v){0.f, 0.f, 0.f, 0.f};
        acc[mt][1] = (float4v){0.f, 0.f, 0.f, 0.f};
    }
    {
        short8 bfr[2][4];
        #pragma unroll
        for (int ks = 0; ks < 4; ++ks) {
            const int k0 = ks * 32 + quad * 8;
            #pragma unroll
            for (int ht = 0; ht < 2; ++ht)
                bfr[ht][ks] = *(const short8*)&Apool[ht * 16 + row][k0];
        }
        #pragma unroll
        for (int mt = 0; mt < 8; ++mt) {
            const unsigned short* wrow = w1t + (size_t)(w * 128 + mt * 16 + row) * DIM;
            #pragma unroll
            for (int ks = 0; ks < 4; ++ks) {
                short8 afr = *(const short8*)(wrow + ks * 32 + quad * 8);
                acc[mt][0] = __builtin_amdgcn_mfma_f32_16x16x32_bf16(afr, bfr[0][ks], acc[mt][0], 0, 0, 0);
                acc[mt][1] = __builtin_amdgcn_mfma_f32_16x16x32_bf16(afr, bfr[1][ks], acc[mt][1], 0, 0, 0);
            }
        }
    }
    // -------- pass 1: bias + ReLU in registers, LN stats --------
    float sum0 = 0.f, ssq0 = 0.f, sum1 = 0.f, ssq1 = 0.f;
    #pragma unroll
    for (int mt = 0; mt < 8; ++mt) {
        const int nb = w * 128 + mt * 16 + quad * 4;
        const float4v bias = *(const float4v*)(b1 + nb);
        #pragma unroll
        for (int r = 0; r < 4; ++r) {
            float v0 = fmaxf(acc[mt][0][r] + bias[r], 0.f);
            float v1 = fmaxf(acc[mt][1][r] + bias[r], 0.f);
            acc[mt][0][r] = v0;  sum0 += v0;  ssq0 += v0 * v0;
            acc[mt][1][r] = v1;  sum1 += v1;  ssq1 += v1 * v1;
        }
    }
    #pragma unroll
    for (int m = 16; m <= 32; m <<= 1) {       // reduce across the 4 quads
        sum0 += __shfl_xor(sum0, m);  ssq0 += __shfl_xor(ssq0, m);
        sum1 += __shfl_xor(sum1, m);  ssq1 += __shfl_xor(ssq1, m);
    }
    if (lane < 16) {
        part[0][row][w][0] = sum0;  part[0][row][w][1] = ssq0;
        part[1][row][w][0] = sum1;  part[1][row][w][1] = ssq1;
    }
    __syncthreads();
    float mu[2], rs[2];
    #pragma unroll
    for (int ht = 0; ht < 2; ++ht) {
        float S = 0.f, Q = 0.f;
        #pragma unroll
        for (int ww = 0; ww < 4; ++ww) {
            S += part[ht][row][ww][0];
            Q += part[ht][row][ww][1];
        }
        const float invn = 1.f / (float)DFF;
        mu[ht] = S * invn;
        float var = Q * invn - mu[ht] * mu[ht];
        rs[ht] = rsqrtf(var + 1e-5f);
    }
    // -------- pass 2: normalize fp32 regs, pack bf16, single LDS write --------
    #pragma unroll
    for (int mt = 0; mt < 8; ++mt) {
        const int nb = w * 128 + mt * 16 + quad * 4;
        const float4v g4  = *(const float4v*)(gamma + nb);
        const float4v be4 = *(const float4v*)(beta + nb);
        #pragma unroll
        for (int ht = 0; ht < 2; ++ht) {
            float o[4];
            #pragma unroll
            for (int r = 0; r < 4; ++r) {
                float tg = rs[ht] * g4[r];
                o[r] = acc[mt][ht][r] * tg + (be4[r] - mu[ht] * tg);
            }
            uint2 p;
            p.x = pk_bf16(o[0], o[1]);
            p.y = pk_bf16(o[2], o[3]);
            *(uint2*)&Hsm[ht * 16 + row][nb] = p;
        }
    }
    __syncthreads();

    // -------- GEMM2 (A=Hs [hop][k] LDS, B=w2t [tt][k] global) --------
    {
        float4v acc2[2];
        acc2[0] = (float4v){0.f,0.f,0.f,0.f};
        acc2[1] = (float4v){0.f,0.f,0.f,0.f};
        #pragma unroll
        for (int ks = 0; ks < 16; ++ks) {
            const int k0 = ks * 32 + quad * 8;
            short8 bfr = *(const short8*)(w2t + (size_t)(w * 16 + row) * DFF + k0);
            #pragma unroll
            for (int mt = 0; mt < 2; ++mt) {
                short8 afr = *(const short8*)&Hsm[mt * 16 + row][k0];
                acc2[mt] = __builtin_amdgcn_mfma_f32_16x16x32_bf16(
                    afr, bfr, acc2[mt], 0, 0, 0);
            }
        }
        const float bb = b2[w * 16 + row];
        #pragma unroll
        for (int mt = 0; mt < 2; ++mt) {
            #pragma unroll
            for (int r = 0; r < 4; ++r) {
                int hop = hop0 + mt * 16 + quad * 4 + r;
                if (hop < H)
                    out[(size_t)hop * TTW + w * 16 + row] = acc2[mt][r] + bb;
            }
        }
    }
}

extern "C" void kernel_launch(void* const* d_in, const int* in_sizes, int n_in,
                              void* d_out, int out_size, void* d_ws, size_t ws_size,
                              hipStream_t stream) {
    const float* hf    = (const float*)d_in[0];
    const float* w_q   = (const float*)d_in[1];
    const float* W1    = (const float*)d_in[2];
    const float* b1    = (const float*)d_in[3];
    const float* gamma = (const float*)d_in[4];
    const float* beta  = (const float*)d_in[5];
    const float* W2    = (const float*)d_in[6];
    const float* b2    = (const float*)d_in[7];
    const int* pi      = (const int*)d_in[8];
    const int* stats   = (const int*)d_in[9];
    const int* po      = (const int*)d_in[10];
    float* out         = (float*)d_out;

    const int n_hf = in_sizes[0];           // N_NODES*128
    const int H    = in_sizes[10];
    const int ntiles = (H + TILE_H - 1) / TILE_H;

    // ws layout
    char* ws = (char*)d_ws;
    unsigned short* w1t = (unsigned short*)ws;                       // 128KB
    unsigned short* w2t = (unsigned short*)(ws + 131072);            // 64KB
    unsigned short* hf2 = (unsigned short*)(ws + 196608);            // n_hf*2

    const int B_HF = (n_hf + 2047) / 2048;   // 8 elems/thread
    hipLaunchKernelGGL(prep_k, dim3(B_HF + 96), dim3(256), 0, stream,
                       hf, W1, W2, hf2, w1t, w2t, n_hf, B_HF);
    hipLaunchKernelGGL(fused_k, dim3(ntiles), dim3(256), 0, stream,
                       hf2, w_q, pi, stats, po, w1t, b1, gamma, beta, w2t, b2, out, H);
}